// Round 19
// baseline (371.967 us; speedup 1.0000x reference)
//
#include <hip/hip_runtime.h>
#include <hip/hip_bf16.h>

#define NN 30000
#define NE 480000
#define ADL 2.8332133440562162f   // ln(17)

typedef unsigned int u32;
typedef unsigned short u16;

typedef _Float16 half2v __attribute__((ext_vector_type(2)));

__device__ __forceinline__ u16 f2h(float f){
  union { _Float16 h; u16 u; } v; v.h = (_Float16)f; return v.u;
}
__device__ __forceinline__ float h2f_lo(u32 u){
  union { u16 us; _Float16 h; } v; v.us = (u16)(u & 0xffff); return (float)v.h;
}
__device__ __forceinline__ float h2f_hi(u32 u){
  union { u16 us; _Float16 h; } v; v.us = (u16)(u >> 16); return (float)v.h;
}
__device__ __forceinline__ u32 pack2(float lo, float hi){
  return (u32)f2h(lo) | ((u32)f2h(hi) << 16);
}
__device__ __forceinline__ float dot2f(u32 a, u32 b, float c){
#if defined(__has_builtin) && __has_builtin(__builtin_amdgcn_fdot2)
  union U { u32 u; half2v h; };
  U ua, ub; ua.u = a; ub.u = b;
  return __builtin_amdgcn_fdot2(ua.h, ub.h, c, false);
#else
  float r;
  asm("v_dot2_f32_f16 %0, %1, %2, %3" : "=v"(r) : "v"(a), "v"(b), "v"(c));
  return r;
#endif
}

// ======================= CSR build =======================
__global__ void k_hist(const int* __restrict__ ei, int* __restrict__ cnt){
  int e = blockIdx.x * blockDim.x + threadIdx.x;
  if (e < NE) atomicAdd(&cnt[ei[NE + e]], 1);
}

__global__ __launch_bounds__(1024) void k_scanA(const int* __restrict__ cnt,
                                                int* __restrict__ off, int* __restrict__ bsum){
  __shared__ int buf[1024];
  const int b = blockIdx.x, tid = threadIdx.x;
  const int i = b*1024 + tid;
  int v = (i < NN) ? cnt[i] : 0;
  buf[tid] = v;
  __syncthreads();
  for (int s = 1; s < 1024; s <<= 1){
    int t = (tid >= s) ? buf[tid - s] : 0;
    __syncthreads();
    buf[tid] += t;
    __syncthreads();
  }
  if (i < NN) off[i] = buf[tid] - v;
  if (tid == 1023) bsum[b] = buf[1023];
}

__global__ void k_scanC(int* __restrict__ off, const int* __restrict__ bsum){
  int i = blockIdx.x * blockDim.x + threadIdx.x;
  if (i < NN){
    int pre = 0;
    const int nb = i >> 10;
    for (int b = 0; b < nb; ++b) pre += bsum[b];
    off[i] += pre;
  }
  if (i == NN) off[NN] = NE;
}

__global__ void k_scatter(const int* __restrict__ ei, const float* __restrict__ eattr,
                          const int* __restrict__ off,
                          int* __restrict__ cursor, int* __restrict__ eids,
                          int* __restrict__ sidC, u32* __restrict__ eattrH){
  int e = blockIdx.x * blockDim.x + threadIdx.x;
  if (e < NE){
    int d = ei[NE + e];
    int pos = off[d] + atomicAdd(&cursor[d], 1);
    eids[pos] = e;
    sidC[pos] = ei[e];
    const float* ar = eattr + (size_t)e * 16;
    u32* dst = eattrH + (size_t)pos * 8;
    #pragma unroll
    for (int q = 0; q < 8; ++q) dst[q] = pack2(ar[2*q], ar[2*q+1]);
  }
}

// ======================= prep: f16 weight packs + x pre-pack + composed ea matrix =======================
__global__ void k_prep(const float* __restrict__ x,
                       const float* __restrict__ preW0, const float* __restrict__ preW1,
                       const float* __restrict__ postW0, const float* __restrict__ postW1,
                       const float* __restrict__ Wlin,
                       const float* __restrict__ Wedge, const float* __restrict__ b_edge,
                       const float* __restrict__ pre_b0,
                       u32* __restrict__ preW0H, u32* __restrict__ preW1H,
                       u32* __restrict__ postW0H, u32* __restrict__ postW1H,
                       u32* __restrict__ WlinH,
                       u16* __restrict__ eaM16, float* __restrict__ pre_b0F,
                       u32* __restrict__ xH)
{
  int i = blockIdx.x * blockDim.x + threadIdx.x;
  if (i < NN * 64){
    const float2 v = *(const float2*)(x + (size_t)i * 2);
    xH[i] = pack2(v.x, v.y);
  }
  if (i < 32768){
    int c = i >> 8, q = i & 255;
    int t = c >> 5, f = c & 31;
    postW0H[i] = pack2(postW0[t*16384 + (2*q)*32 + f], postW0[t*16384 + (2*q+1)*32 + f]);
  }
  if (i < 8192){
    int c = i >> 6, q = i & 63;
    WlinH[i] = pack2(Wlin[(2*q)*128 + c], Wlin[(2*q+1)*128 + c]);
  }
  if (i < 4096){
    int c = i >> 5, q = i & 31;
    int t = c >> 5, f = c & 31;
    preW0H[i] = pack2(preW0[t*3072 + (2*q)*32 + f], preW0[t*3072 + (2*q+1)*32 + f]);
  }
  if (i < 2048){
    int c = i >> 4, q = i & 15;
    int t = c >> 5, f = c & 31;
    preW1H[i] = pack2(preW1[t*1024 + (2*q)*32 + f], preW1[t*1024 + (2*q+1)*32 + f]);
  }
  if (i < 2048){
    int c = i >> 4, q = i & 15;
    int t = c >> 5, f = c & 31;
    postW1H[i] = pack2(postW1[t*1024 + (2*q)*32 + f], postW1[t*1024 + (2*q+1)*32 + f]);
  }
  if (i < 2048){
    int c = i >> 4, kk = i & 15;
    int t = c >> 5, f = c & 31;
    float acc = 0.f;
    #pragma unroll 8
    for (int g = 0; g < 32; ++g)
      acc = fmaf(Wedge[kk*32 + g], preW0[t*3072 + (64+g)*32 + f], acc);
    eaM16[c*16 + kk] = f2h(acc);
  }
  if (i < 128){
    int t = i >> 5, f = i & 31;
    float acc = pre_b0[i];
    #pragma unroll 8
    for (int g = 0; g < 32; ++g)
      acc = fmaf(b_edge[g], preW0[t*3072 + (64+g)*32 + f], acc);
    pre_b0F[i] = acc;
  }
}

// ======================= fused edge+post: 8 nodes/block, agg stays in LDS =======================
// Edge phase = R18's proven k_edge4 (208us); post phase = R18's k_post2 at N=8.
// Fusion removes the 62MB aggP round-trip + 1 launch; co-resident blocks in different
// phases (latency-heavy edge vs VALU-dense post) hide each other's stalls.
__global__ __launch_bounds__(128, 2) void k_fused(
  const float* __restrict__ x,
  const u32* __restrict__ xHu,
  const u32* __restrict__ atHu,
  const int* __restrict__ sidC,
  const u32* __restrict__ preW0H, const u32* __restrict__ preW1H,
  const u32* __restrict__ eaMu,
  const float* __restrict__ pre_b0F, const float* __restrict__ pre_b1,
  const u32* __restrict__ postW0H, const u32* __restrict__ postW1H,
  const u32* __restrict__ WlinH,
  const float* __restrict__ post_b0, const float* __restrict__ post_b1,
  const float* __restrict__ b_lin, const float* __restrict__ ln_g,
  const float* __restrict__ ln_b,
  const int* __restrict__ off,
  float* __restrict__ out)
{
  const int c = threadIdx.x;        // channel 0..127
  const int t = c >> 5;             // tower
  const int n0 = blockIdx.x * 8;

  __shared__ __align__(16) u32 xdA[8][64];        // all 8 dst rows (packed)
  __shared__ __align__(16) u32 xsH[2][4][64];
  __shared__ __align__(16) u32 atS[2][4][8];
  __shared__ __align__(16) u32 hP[4][64];
  __shared__ __align__(16) u32 aggL[8][6][64];    // 0=sum 1=mean 2=mn 3=mx 4=sd 5=sq
  __shared__ __align__(16) u32 hpP[8][64];
  __shared__ __align__(16) u32 vP[8][64];
  __shared__ __align__(16) float lnS[8][128];
  __shared__ int sidS[64];
  __shared__ int offS[9];
  __shared__ float s1S[8], s2S[8], muS[8], rsS[8];

  // block-start staging: 8 dst rows + offsets
  #pragma unroll
  for (int k = 0; k < 4; ++k){
    const int idx = k*128 + c;
    xdA[idx >> 6][idx & 63] = xHu[(size_t)(n0 + (idx >> 6))*64 + (idx & 63)];
  }
  if (c < 9) offS[c] = off[n0 + c];

  u32 w0p[32], w1p[16], wea[8];
  #pragma unroll
  for (int q = 0; q < 8; ++q) *(uint4*)&w0p[q*4] = *(const uint4*)(preW0H + (size_t)c*32 + q*4);
  #pragma unroll
  for (int q = 0; q < 4; ++q) *(uint4*)&w1p[q*4] = *(const uint4*)(preW1H + (size_t)c*16 + q*4);
  #pragma unroll
  for (int q = 0; q < 2; ++q) *(uint4*)&wea[q*4] = *(const uint4*)(eaMu + (size_t)c*8 + q*4);
  const float pb0 = pre_b0F[c];
  const float pb1 = pre_b1[c];

  const int el = c >> 6;
  const int eh = el + 2;
  const int col = c & 63;
  __syncthreads();

  // =============== EDGE PHASE (R18 structure, agg -> LDS) ===============
  for (int nn = 0; nn < 8; ++nn){
    __syncthreads();                 // protect xsH/hP from previous node
    const int e0 = offS[nn], e1 = offS[nn+1];
    float sum = 0.f, sq = 0.f;
    float mn = __builtin_inff(), mx = -__builtin_inff();

    for (int base = e0; base < e1; base += 64){
      const int nv = min(64, e1 - base);
      if (c < nv) sidS[c] = sidC[base + c];
      __syncthreads();

      float a0n = pb0;
      #pragma unroll
      for (int i4 = 0; i4 < 4; ++i4){
        const uint4 xv = *(const uint4*)&xdA[nn][t*16 + i4*4];
        a0n = dot2f(xv.x, w0p[i4*4+0], a0n);
        a0n = dot2f(xv.y, w0p[i4*4+1], a0n);
        a0n = dot2f(xv.z, w0p[i4*4+2], a0n);
        a0n = dot2f(xv.w, w0p[i4*4+3], a0n);
      }

      const int np = (nv + 3) >> 2;

      {
        const int g0 = min(el, nv-1), g1 = min(eh, nv-1);
        xsH[0][el][col] = xHu[(size_t)sidS[g0]*64 + col];
        xsH[0][eh][col] = xHu[(size_t)sidS[g1]*64 + col];
        if (c < 32){
          const int e = c >> 3, q = c & 7;
          atS[0][e][q] = atHu[(size_t)(base + min(e, nv-1))*8 + q];
        }
      }
      __syncthreads();

      for (int p = 0; p < np; ++p){
        const int buf = p & 1;
        const int sub = p * 4;
        const bool hasNext = (p + 1 < np);

        u32 nxs0 = 0, nxs1 = 0, nat = 0;
        if (hasNext){
          const int s2 = sub + 4;
          const int g0 = min(s2 + el, nv-1), g1 = min(s2 + eh, nv-1);
          nxs0 = xHu[(size_t)sidS[g0]*64 + col];
          nxs1 = xHu[(size_t)sidS[g1]*64 + col];
          if (c < 32){
            const int e = c >> 3, q = c & 7;
            nat = atHu[(size_t)(base + min(s2 + e, nv-1))*8 + q];
          }
        }

        float aXs[4] = {0,0,0,0}, aEa[4] = {0,0,0,0};
        #pragma unroll
        for (int i4 = 0; i4 < 4; ++i4){
          uint4 xsv[4];
          #pragma unroll
          for (int e = 0; e < 4; ++e)
            xsv[e] = *(const uint4*)&xsH[buf][e][t*16 + i4*4];
          const u32 wx0 = w0p[16+i4*4+0], wx1 = w0p[16+i4*4+1];
          const u32 wx2 = w0p[16+i4*4+2], wx3 = w0p[16+i4*4+3];
          #pragma unroll
          for (int e = 0; e < 4; ++e){
            aXs[e] = dot2f(xsv[e].x, wx0, aXs[e]);
            aXs[e] = dot2f(xsv[e].y, wx1, aXs[e]);
            aXs[e] = dot2f(xsv[e].z, wx2, aXs[e]);
            aXs[e] = dot2f(xsv[e].w, wx3, aXs[e]);
          }
        }
        #pragma unroll
        for (int i4 = 0; i4 < 2; ++i4){
          uint4 eav[4];
          #pragma unroll
          for (int e = 0; e < 4; ++e)
            eav[e] = *(const uint4*)&atS[buf][e][i4*4];
          const u32 we0 = wea[i4*4+0], we1 = wea[i4*4+1];
          const u32 we2 = wea[i4*4+2], we3 = wea[i4*4+3];
          #pragma unroll
          for (int e = 0; e < 4; ++e){
            aEa[e] = dot2f(eav[e].x, we0, aEa[e]);
            aEa[e] = dot2f(eav[e].y, we1, aEa[e]);
            aEa[e] = dot2f(eav[e].z, we2, aEa[e]);
            aEa[e] = dot2f(eav[e].w, we3, aEa[e]);
          }
        }
        #pragma unroll
        for (int e = 0; e < 4; ++e){
          const float h = fmaxf(a0n + aXs[e] + aEa[e], 0.f);
          const u32 mine = (u32)f2h(h);
          const u32 oth  = (u32)__shfl_xor((int)mine, 1);
          if ((c & 1) == 0) hP[e][c >> 1] = mine | (oth << 16);
        }

        float mm[4] = {pb1, pb1, pb1, pb1};
        #pragma unroll
        for (int i4 = 0; i4 < 4; ++i4){
          uint4 hv[4];
          #pragma unroll
          for (int e = 0; e < 4; ++e) hv[e] = *(const uint4*)&hP[e][t*16 + i4*4];
          const u32 w0v = w1p[i4*4+0], w1v = w1p[i4*4+1];
          const u32 w2v = w1p[i4*4+2], w3v = w1p[i4*4+3];
          #pragma unroll
          for (int e = 0; e < 4; ++e){
            mm[e] = dot2f(hv[e].x, w0v, mm[e]);
            mm[e] = dot2f(hv[e].y, w1v, mm[e]);
            mm[e] = dot2f(hv[e].z, w2v, mm[e]);
            mm[e] = dot2f(hv[e].w, w3v, mm[e]);
          }
        }
        #pragma unroll
        for (int e = 0; e < 4; ++e){
          if (sub + e < nv){
            sum += mm[e]; sq = fmaf(mm[e], mm[e], sq);
            mn = fminf(mn, mm[e]); mx = fmaxf(mx, mm[e]);
          }
        }

        if (hasNext){
          xsH[buf^1][el][col] = nxs0;
          xsH[buf^1][eh][col] = nxs1;
          if (c < 32){ const int e = c >> 3, q = c & 7; atS[buf^1][e][q] = nat; }
        }
        __syncthreads();
      }
    }

    const int deg = e1 - e0;
    const float mnz = (deg > 0) ? mn : 0.f;
    const float mxz = (deg > 0) ? mx : 0.f;
    const u32 sm = (u32)f2h(sum),  so = (u32)__shfl_xor((int)sm, 1);
    const u32 qm = (u32)f2h(sq),   qo = (u32)__shfl_xor((int)qm, 1);
    const u32 nm = (u32)f2h(mnz),  no = (u32)__shfl_xor((int)nm, 1);
    const u32 xm = (u32)f2h(mxz),  xo = (u32)__shfl_xor((int)xm, 1);
    if ((c & 1) == 0){
      const int j = c >> 1;
      aggL[nn][0][j] = sm | (so << 16);
      aggL[nn][5][j] = qm | (qo << 16);
      aggL[nn][2][j] = nm | (no << 16);
      aggL[nn][3][j] = xm | (xo << 16);
    }
  }

  // =============== POST PHASE (R18 k_post2 structure, N=8, LDS agg) ===============
  __syncthreads();
  #pragma unroll
  for (int k = 0; k < 4; ++k){           // mean + sd packs
    const int idx = k*128 + c;
    const int n = idx >> 6, j = idx & 63;
    const int deg = offS[n+1] - offS[n];
    const float denom = fmaxf((float)deg, 1.f);
    const u32 sp = aggL[n][0][j];
    const u32 qp = aggL[n][5][j];
    const float me0 = h2f_lo(sp)/denom, me1 = h2f_hi(sp)/denom;
    const float sd0 = sqrtf(fmaxf(h2f_lo(qp)/denom - me0*me0, 0.f) + 1e-5f);
    const float sd1 = sqrtf(fmaxf(h2f_hi(qp)/denom - me1*me1, 0.f) + 1e-5f);
    aggL[n][1][j] = pack2(me0, me1);
    aggL[n][4][j] = pack2(sd0, sd1);
  }
  if (c < 8){
    int deg = offS[c+1] - offS[c];
    float logd = logf(fmaxf((float)deg, 1.f) + 1.f);
    s1S[c] = logd / ADL; s2S[c] = ADL / logd;
  }
  __syncthreads();

  // layer0 (dot2, weights streamed; register-tiled over 8 nodes)
  float acc[8], pa1[8], pa2[8];
  const float pb0p = post_b0[c];
  #pragma unroll
  for (int n = 0; n < 8; ++n){ acc[n] = pb0p; pa1[n] = 0.f; pa2[n] = 0.f; }
  const u32* Wp = postW0H + (size_t)c * 256;
  #pragma unroll
  for (int q4 = 0; q4 < 4; ++q4){
    const uint4 w = *(const uint4*)(Wp + q4*4);
    #pragma unroll
    for (int n = 0; n < 8; ++n){
      const uint4 av = *(const uint4*)&xdA[n][t*16 + q4*4];
      acc[n] = dot2f(av.x, w.x, acc[n]); acc[n] = dot2f(av.y, w.y, acc[n]);
      acc[n] = dot2f(av.z, w.z, acc[n]); acc[n] = dot2f(av.w, w.w, acc[n]);
    }
  }
  for (int a = 0; a < 5; ++a){
    #pragma unroll
    for (int q4 = 0; q4 < 4; ++q4){
      const uint4 wI = *(const uint4*)(Wp + 16  + a*16 + q4*4);
      const uint4 wA = *(const uint4*)(Wp + 96  + a*16 + q4*4);
      const uint4 wT = *(const uint4*)(Wp + 176 + a*16 + q4*4);
      #pragma unroll
      for (int n = 0; n < 8; ++n){
        const uint4 av = *(const uint4*)&aggL[n][a][t*16 + q4*4];
        acc[n] = dot2f(av.x, wI.x, acc[n]); acc[n] = dot2f(av.y, wI.y, acc[n]);
        acc[n] = dot2f(av.z, wI.z, acc[n]); acc[n] = dot2f(av.w, wI.w, acc[n]);
        pa1[n] = dot2f(av.x, wA.x, pa1[n]); pa1[n] = dot2f(av.y, wA.y, pa1[n]);
        pa1[n] = dot2f(av.z, wA.z, pa1[n]); pa1[n] = dot2f(av.w, wA.w, pa1[n]);
        pa2[n] = dot2f(av.x, wT.x, pa2[n]); pa2[n] = dot2f(av.y, wT.y, pa2[n]);
        pa2[n] = dot2f(av.z, wT.z, pa2[n]); pa2[n] = dot2f(av.w, wT.w, pa2[n]);
      }
    }
  }
  #pragma unroll
  for (int n = 0; n < 8; ++n){
    const float hp = fmaxf(acc[n] + s1S[n]*pa1[n] + s2S[n]*pa2[n], 0.f);
    const u32 mine = (u32)f2h(hp);
    const u32 oth  = (u32)__shfl_xor((int)mine, 1);
    if ((c & 1) == 0) hpP[n][c >> 1] = mine | (oth << 16);
  }
  __syncthreads();

  // layer1 (dot2, weights in regs)
  u32 w1q[16];
  #pragma unroll
  for (int q = 0; q < 4; ++q) *(uint4*)&w1q[q*4] = *(const uint4*)(postW1H + (size_t)c*16 + q*4);
  const float pb1v = post_b1[c];
  #pragma unroll
  for (int n = 0; n < 8; ++n){
    float a2 = pb1v;
    #pragma unroll
    for (int q4 = 0; q4 < 4; ++q4){
      const uint4 hv = *(const uint4*)&hpP[n][t*16 + q4*4];
      a2 = dot2f(hv.x, w1q[q4*4+0], a2); a2 = dot2f(hv.y, w1q[q4*4+1], a2);
      a2 = dot2f(hv.z, w1q[q4*4+2], a2); a2 = dot2f(hv.w, w1q[q4*4+3], a2);
    }
    const u32 mine = (u32)f2h(a2);
    const u32 oth  = (u32)__shfl_xor((int)mine, 1);
    if ((c & 1) == 0) vP[n][c >> 1] = mine | (oth << 16);
  }
  __syncthreads();

  // final linear H->H
  float a3[8];
  const float blv = b_lin[c];
  #pragma unroll
  for (int n = 0; n < 8; ++n) a3[n] = blv;
  const u32* Wl = WlinH + (size_t)c * 64;
  #pragma unroll 4
  for (int q4 = 0; q4 < 16; ++q4){
    const uint4 w = *(const uint4*)(Wl + q4*4);
    #pragma unroll
    for (int n = 0; n < 8; ++n){
      const uint4 vv = *(const uint4*)&vP[n][q4*4];
      a3[n] = dot2f(vv.x, w.x, a3[n]); a3[n] = dot2f(vv.y, w.y, a3[n]);
      a3[n] = dot2f(vv.z, w.z, a3[n]); a3[n] = dot2f(vv.w, w.w, a3[n]);
    }
  }

  // LayerNorm (f32): 16 threads per node, 8 elems each
  #pragma unroll
  for (int n = 0; n < 8; ++n) lnS[n][c] = a3[n];
  __syncthreads();
  {
    const int n = c >> 4, seg = c & 15;
    float ps = 0.f, ps2 = 0.f;
    #pragma unroll
    for (int k = 0; k < 8; ++k){
      float v = lnS[n][seg*8 + k];
      ps += v; ps2 = fmaf(v, v, ps2);
    }
    ps += __shfl_xor(ps, 1); ps2 += __shfl_xor(ps2, 1);
    ps += __shfl_xor(ps, 2); ps2 += __shfl_xor(ps2, 2);
    ps += __shfl_xor(ps, 4); ps2 += __shfl_xor(ps2, 4);
    ps += __shfl_xor(ps, 8); ps2 += __shfl_xor(ps2, 8);
    if (seg == 0){
      float mu = ps * (1.f/128.f);
      float var = fmaxf(ps2 * (1.f/128.f) - mu*mu, 0.f);
      muS[n] = mu; rsS[n] = rsqrtf(var + 1e-5f);
    }
  }
  __syncthreads();
  const float gv = ln_g[c], bv = ln_b[c];
  #pragma unroll
  for (int n = 0; n < 8; ++n){
    const size_t nb = (size_t)(n0 + n);
    out[nb*128 + c] = x[nb*128 + c] + fmaxf((a3[n] - muS[n])*rsS[n]*gv + bv, 0.f);
  }
}

// ======================= fallback: proven monolithic kernel (R3, f32) =======================
__global__ __launch_bounds__(128) void k_mono(
  const float* __restrict__ x, const int* __restrict__ ei,
  const float* __restrict__ eattr,
  const float* __restrict__ Wedge, const float* __restrict__ b_edge,
  const float* __restrict__ preW0, const float* __restrict__ pre_b0,
  const float* __restrict__ preW1, const float* __restrict__ pre_b1,
  const float* __restrict__ postW0, const float* __restrict__ post_b0,
  const float* __restrict__ postW1, const float* __restrict__ post_b1,
  const float* __restrict__ Wlin, const float* __restrict__ b_lin,
  const float* __restrict__ ln_g, const float* __restrict__ ln_b,
  const int* __restrict__ off, const int* __restrict__ eids,
  float* __restrict__ out)
{
  const int n = blockIdx.x;
  const int c = threadIdx.x;
  const int t = c >> 5, f = c & 31;
  __shared__ float xdS[128], xsS[128], eaS[32], hS[128];
  __shared__ float aggS[5][128], hpS[128], vS[128], red[4];

  const float xd = x[(size_t)n*128 + c];
  xdS[c] = xd;
  const int e0 = off[n], e1 = off[n+1];
  const int deg = e1 - e0;
  float sum = 0.f, sq = 0.f, mn = __builtin_inff(), mx = -__builtin_inff();
  __syncthreads();

  for (int idx = e0; idx < e1; ++idx){
    const int e = eids[idx];
    const int s = ei[e];
    xsS[c] = x[(size_t)s*128 + c];
    if (c < 32){
      float acc = b_edge[c];
      #pragma unroll
      for (int ii = 0; ii < 16; ++ii) acc = fmaf(eattr[(size_t)e*16 + ii], Wedge[ii*32 + c], acc);
      eaS[c] = acc;
    }
    __syncthreads();
    float acc = pre_b0[c];
    const float* W0 = preW0 + t*3072 + f;
    #pragma unroll 8
    for (int k = 0; k < 32; ++k) acc = fmaf(xdS[t*32+k], W0[k*32], acc);
    #pragma unroll 8
    for (int k = 0; k < 32; ++k) acc = fmaf(xsS[t*32+k], W0[(32+k)*32], acc);
    #pragma unroll 8
    for (int k = 0; k < 32; ++k) acc = fmaf(eaS[k], W0[(64+k)*32], acc);
    hS[c] = fmaxf(acc, 0.f);
    __syncthreads();
    float m = pre_b1[c];
    const float* W1 = preW1 + t*1024 + f;
    #pragma unroll 8
    for (int g = 0; g < 32; ++g) m = fmaf(hS[t*32+g], W1[g*32], m);
    sum += m; sq = fmaf(m, m, sq); mn = fminf(mn, m); mx = fmaxf(mx, m);
    __syncthreads();
  }
  const float d = (float)deg;
  const float denom = fmaxf(d, 1.f);
  const float mean = sum / denom;
  const float sd = sqrtf(fmaxf(sq/denom - mean*mean, 0.f) + 1e-5f);
  const float mnz = (deg > 0) ? mn : 0.f;
  const float mxz = (deg > 0) ? mx : 0.f;
  const float logd = logf(denom + 1.f);
  const float s1 = logd / ADL, s2 = ADL / logd;
  aggS[0][c] = sum; aggS[1][c] = mean; aggS[2][c] = mnz; aggS[3][c] = mxz; aggS[4][c] = sd;
  __syncthreads();
  float acc0 = post_b0[c];
  const float* P0 = postW0 + t*16384 + f;
  #pragma unroll 8
  for (int k = 0; k < 32; ++k) acc0 = fmaf(xdS[t*32+k], P0[k*32], acc0);
  float pa0 = 0.f, pa1 = 0.f, pa2 = 0.f;
  for (int a = 0; a < 5; ++a){
    const float* ag = &aggS[a][t*32];
    const float* Pb = P0 + (32 + a*32)*32;
    #pragma unroll 8
    for (int k = 0; k < 32; ++k){
      const float av = ag[k];
      pa0 = fmaf(av, Pb[k*32], pa0);
      pa1 = fmaf(av, Pb[(160+k)*32], pa1);
      pa2 = fmaf(av, Pb[(320+k)*32], pa2);
    }
  }
  hpS[c] = fmaxf(acc0 + pa0 + s1*pa1 + s2*pa2, 0.f);
  __syncthreads();
  float v = post_b1[c];
  const float* PW1 = postW1 + t*1024 + f;
  #pragma unroll 8
  for (int g = 0; g < 32; ++g) v = fmaf(hpS[t*32+g], PW1[g*32], v);
  vS[c] = v;
  __syncthreads();
  float l = b_lin[c];
  #pragma unroll 8
  for (int k = 0; k < 128; ++k) l = fmaf(vS[k], Wlin[k*128 + c], l);
  float ps = l, ps2 = l*l;
  #pragma unroll
  for (int o = 32; o >= 1; o >>= 1){ ps += __shfl_xor(ps, o); ps2 += __shfl_xor(ps2, o); }
  if ((c & 63) == 0){ red[c>>6] = ps; red[2 + (c>>6)] = ps2; }
  __syncthreads();
  const float mu = (red[0] + red[1]) * (1.f/128.f);
  const float var = fmaxf((red[2] + red[3]) * (1.f/128.f) - mu*mu, 0.f);
  const float rstd = rsqrtf(var + 1e-5f);
  out[(size_t)n*128 + c] = xd + fmaxf((l - mu)*rstd*ln_g[c] + ln_b[c], 0.f);
}

// ======================= launch =======================
extern "C" void kernel_launch(void* const* d_in, const int* in_sizes, int n_in,
                              void* d_out, int out_size, void* d_ws, size_t ws_size,
                              hipStream_t stream){
  const float* x       = (const float*)d_in[0];
  const int*   ei      = (const int*)d_in[1];
  const float* eattr   = (const float*)d_in[2];
  const float* Wedge   = (const float*)d_in[3];
  const float* b_edge  = (const float*)d_in[4];
  const float* preW0   = (const float*)d_in[5];
  const float* pre_b0  = (const float*)d_in[6];
  const float* preW1   = (const float*)d_in[7];
  const float* pre_b1  = (const float*)d_in[8];
  const float* postW0  = (const float*)d_in[9];
  const float* post_b0 = (const float*)d_in[10];
  const float* postW1  = (const float*)d_in[11];
  const float* post_b1 = (const float*)d_in[12];
  const float* Wlin    = (const float*)d_in[13];
  const float* b_lin   = (const float*)d_in[14];
  const float* ln_g    = (const float*)d_in[15];
  const float* ln_b    = (const float*)d_in[16];

  char* ws = (char*)d_ws;
  size_t o = 0;
  auto alloc = [&](size_t bytes)->char*{
    char* p = ws + o; o = (o + bytes + 255) & ~((size_t)255); return p;
  };
  int* off    = (int*)alloc((NN + 1) * 4);
  int* cnt    = (int*)alloc(NN * 4);
  int* cursor = (int*)alloc(NN * 4);
  int* eids   = (int*)alloc(NE * 4);
  int* sidc   = (int*)alloc(NE * 4);
  int* bsum   = (int*)alloc(32 * 4);
  u32* preW0H  = (u32*)alloc(4096 * 4);
  u32* preW1H  = (u32*)alloc(2048 * 4);
  u32* postW0H = (u32*)alloc(32768 * 4);
  u32* postW1H = (u32*)alloc(2048 * 4);
  u32* WlinH   = (u32*)alloc(8192 * 4);
  u16* eaM16   = (u16*)alloc(2048 * 2);
  float* pre_b0F = (float*)alloc(128 * 4);
  u32* eattrH  = (u32*)alloc((size_t)NE * 8 * 4);
  u32* xH      = (u32*)alloc((size_t)NN * 64 * 4);
  const size_t need = o;

  // CSR build
  hipMemsetAsync(cnt, 0, NN * 4, stream);
  hipMemsetAsync(cursor, 0, NN * 4, stream);
  k_hist<<<(NE + 255)/256, 256, 0, stream>>>(ei, cnt);
  k_scanA<<<30, 1024, 0, stream>>>(cnt, off, bsum);
  k_scanC<<<(NN + 256)/256, 256, 0, stream>>>(off, bsum);
  k_scatter<<<(NE + 255)/256, 256, 0, stream>>>(ei, eattr, off, cursor, eids, sidc, eattrH);

  if (ws_size < need){
    k_mono<<<NN, 128, 0, stream>>>(x, ei, eattr, Wedge, b_edge,
                                   preW0, pre_b0, preW1, pre_b1,
                                   postW0, post_b0, postW1, post_b1,
                                   Wlin, b_lin, ln_g, ln_b,
                                   off, eids, (float*)d_out);
    return;
  }

  k_prep<<<(NN*64 + 255)/256, 256, 0, stream>>>(x, preW0, preW1, postW0, postW1, Wlin,
                                                Wedge, b_edge, pre_b0,
                                                preW0H, preW1H, postW0H, postW1H, WlinH,
                                                eaM16, pre_b0F, xH);
  k_fused<<<NN/8, 128, 0, stream>>>(x, xH, eattrH, sidc, preW0H, preW1H,
                                    (const u32*)eaM16, pre_b0F, pre_b1,
                                    postW0H, postW1H, WlinH,
                                    post_b0, post_b1, b_lin, ln_g, ln_b,
                                    off, (float*)d_out);
}